// Round 8
// baseline (442.677 us; speedup 1.0000x reference)
//
#include <hip/hip_runtime.h>

// AvgSPP: x (16,256,256,64) f32 NHWC. SCALE=8 -> uniform 32x32 bins
// (half-pixel-center NN formula degenerates to bin = (h>>5, w>>5) at 256/8),
// and s^2/(h*w) = 1/1024 = 1/bin_pixel_count -> out = per-bin mean broadcast.
//
// Fused one-pass, one block per (b,u,v) bin: read 256 KB -> reduce -> write
// the 64 channel-means over the bin's own 32x32 output block.
// 512 thr/block (8 waves) x 1024 blocks = 4 blocks/CU x 8 = 32 waves/CU (max).
// Thread t: c4 = t&15 (float4 channel group, C=64), ph = t>>4 (bin col, 0..31).
// At each row k the block touches 32 px * 256 B = 8 KB contiguous; per-wave
// vector load = 64 lanes * 16 B = 1 KB contiguous (coalescing sweet spot).

typedef float f32x4 __attribute__((ext_vector_type(4)));  // clang vector: OK for
                                                          // __builtin_nontemporal_*

__global__ __launch_bounds__(512) void spp_fused(const f32x4* __restrict__ x4,
                                                 f32x4* __restrict__ out4) {
    const int bin = blockIdx.x;          // [0, 16*8*8)
    const int v = bin & 7;               // bin col
    const int u = (bin >> 3) & 7;        // bin row
    const int b = bin >> 6;              // batch
    const int t = threadIdx.x;
    const int c4 = t & 15;               // float4 channel group
    const int ph = t >> 4;               // bin column this thread owns [0,32)

    // float4 index of pixel (b, u*32, v*32 + ph), channel group c4
    const int base = ((b * 256 + u * 32) * 256 + v * 32 + ph) * 16 + c4;
    const f32x4* __restrict__ src = x4 + base;

    f32x4 acc = (f32x4)(0.f);
    #pragma unroll 8
    for (int k = 0; k < 32; ++k) {       // k = row within bin; stride = 1 image row
        acc += __builtin_nontemporal_load(src + k * 256 * 16);
    }

    // Intra-wave reduce: lane bits 4,5 select the 4 ph-values this wave holds.
    #pragma unroll
    for (int m = 16; m <= 32; m <<= 1) {
        acc.x += __shfl_xor(acc.x, m);
        acc.y += __shfl_xor(acc.y, m);
        acc.z += __shfl_xor(acc.z, m);
        acc.w += __shfl_xor(acc.w, m);
    }

    // Cross-wave reduce: 8 waves x 16 channel-groups in LDS.
    __shared__ f32x4 red[8][16];
    const int wave = t >> 6;
    if ((t & 63) < 16) red[wave][c4] = acc;   // lane<16 holds the wave partial
    __syncthreads();
    if (t < 128) {                            // c4 = t&15, w = t>>4 in [0,8)
        const int w = t >> 4;
        for (int s = 4; s >= 1; s >>= 1) {
            if (w < s) {
                red[w][c4] += red[w + s][c4];
            }
            __syncthreads();
        }
    } else {
        for (int s = 4; s >= 1; s >>= 1) __syncthreads();
    }

    f32x4 m = red[0][c4] * (1.0f / 1024.0f);  // = s*s/(h*w) = 1/bin_pixel_count

    f32x4* __restrict__ dst = out4 + base;
    #pragma unroll 8
    for (int k = 0; k < 32; ++k) {
        __builtin_nontemporal_store(m, dst + k * 256 * 16);
    }
}

extern "C" void kernel_launch(void* const* d_in, const int* in_sizes, int n_in,
                              void* d_out, int out_size, void* d_ws, size_t ws_size,
                              hipStream_t stream) {
    const f32x4* x4   = (const f32x4*)d_in[0];
    f32x4*       out4 = (f32x4*)d_out;
    spp_fused<<<dim3(16 * 8 * 8), dim3(512), 0, stream>>>(x4, out4);
}